// Round 1
// baseline (520.055 us; speedup 1.0000x reference)
//
#include <hip/hip_runtime.h>
#include <hip/hip_bf16.h>

#define BB 4
#define NN 8192
#define DD 512
#define EE 8
#define OUTD 512
#define TOPM 1024
#define EPSV 1e-6f
#define ITERS 8

// ---------------- gate logits -> t0 = log(max(x@gw, eps)) ----------------
__global__ __launch_bounds__(256) void k_gate(const float* __restrict__ x,
                                              const float* __restrict__ gw,
                                              float* __restrict__ t0) {
  const int lane = threadIdx.x & 63;
  const int wid  = threadIdx.x >> 6;
  const long row = (long)blockIdx.x * 4 + wid;   // B*N rows, grid=8192
  const float* xr = x + row * DD + lane * 8;
  float4 xa = *(const float4*)(xr);
  float4 xb = *(const float4*)(xr + 4);
  float xv[8] = {xa.x, xa.y, xa.z, xa.w, xb.x, xb.y, xb.z, xb.w};
  float acc[8] = {0.f,0.f,0.f,0.f,0.f,0.f,0.f,0.f};
  const float* gbase = gw + (lane * 8) * EE;
#pragma unroll
  for (int j = 0; j < 8; ++j) {
    float4 g0 = *(const float4*)(gbase + j * EE);
    float4 g1 = *(const float4*)(gbase + j * EE + 4);
    acc[0] += xv[j] * g0.x; acc[1] += xv[j] * g0.y;
    acc[2] += xv[j] * g0.z; acc[3] += xv[j] * g0.w;
    acc[4] += xv[j] * g1.x; acc[5] += xv[j] * g1.y;
    acc[6] += xv[j] * g1.z; acc[7] += xv[j] * g1.w;
  }
#pragma unroll
  for (int off = 32; off; off >>= 1) {
#pragma unroll
    for (int e = 0; e < 8; ++e) acc[e] += __shfl_xor(acc[e], off);
  }
  if (lane < 8) t0[row * EE + lane] = logf(fmaxf(acc[lane], EPSV));
}

// ---------------- Sinkhorn column step: C[b,e] = LSE_n(t0 - R) ----------------
__global__ __launch_bounds__(256) void k_col(const float* __restrict__ t0,
                                             const float* __restrict__ R,
                                             float* __restrict__ C) {
  const int b = blockIdx.x >> 3, e = blockIdx.x & 7;
  const float* t = t0 + (long)b * NN * EE + e;
  const float* Rb = R + b * NN;
  float m = -1e30f, s = 0.f;
  for (int n = threadIdx.x; n < NN; n += 256) {
    float v = t[n * EE] - Rb[n];
    if (v > m) { s = s * expf(m - v) + 1.f; m = v; }
    else       { s += expf(v - m); }
  }
#pragma unroll
  for (int off = 32; off; off >>= 1) {
    float mo = __shfl_xor(m, off), so = __shfl_xor(s, off);
    float M = fmaxf(m, mo);
    s = s * expf(m - M) + so * expf(mo - M);
    m = M;
  }
  __shared__ float sm[4], ss[4];
  if ((threadIdx.x & 63) == 0) { sm[threadIdx.x >> 6] = m; ss[threadIdx.x >> 6] = s; }
  __syncthreads();
  if (threadIdx.x == 0) {
    float M = fmaxf(fmaxf(sm[0], sm[1]), fmaxf(sm[2], sm[3]));
    float S = ss[0]*expf(sm[0]-M) + ss[1]*expf(sm[1]-M) +
              ss[2]*expf(sm[2]-M) + ss[3]*expf(sm[3]-M);
    C[blockIdx.x] = M + logf(S);
  }
}

// ---------------- Sinkhorn row step: R[b,n] = LSE_e(t0 - C) ----------------
__global__ __launch_bounds__(256) void k_row(const float* __restrict__ t0,
                                             const float* __restrict__ C,
                                             float* __restrict__ R) {
  const long i = (long)blockIdx.x * 256 + threadIdx.x;   // < B*N, grid=128
  const int b = (int)(i >> 13);
  float4 a = *(const float4*)(t0 + i * 8);
  float4 bb = *(const float4*)(t0 + i * 8 + 4);
  const float* Cb = C + b * 8;
  float v[8] = {a.x - Cb[0], a.y - Cb[1], a.z - Cb[2], a.w - Cb[3],
                bb.x - Cb[4], bb.y - Cb[5], bb.z - Cb[6], bb.w - Cb[7]};
  float m = v[0];
#pragma unroll
  for (int e = 1; e < 8; ++e) m = fmaxf(m, v[e]);
  float s = 0.f;
#pragma unroll
  for (int e = 0; e < 8; ++e) s += expf(v[e] - m);
  R[i] = m + logf(s);
}

// ---------------- exact top-1024 per (b,e) column via radix select ----------------
__global__ __launch_bounds__(256) void k_topk(const float* __restrict__ t0,
                                              const float* __restrict__ R,
                                              int* __restrict__ expert_of) {
  __shared__ unsigned key[NN];
  __shared__ int hist[256];
  __shared__ int bcast[2];
  __shared__ int tiecnt[256];
  const int b = blockIdx.x >> 3, e = blockIdx.x & 7;
  const int tid = threadIdx.x;
  const float* t = t0 + (long)b * NN * EE + e;
  const float* Rb = R + b * NN;
  for (int n = tid; n < NN; n += 256) {
    float f = t[n * EE] - Rb[n];
    unsigned u = __float_as_uint(f);
    u = (u & 0x80000000u) ? ~u : (u | 0x80000000u);   // sortable: larger u = larger f
    key[n] = u;
  }
  __syncthreads();
  unsigned prefix = 0, mask = 0;
  int k = TOPM;
  for (int shift = 24; shift >= 0; shift -= 8) {
    hist[tid] = 0;
    __syncthreads();
    for (int n = tid; n < NN; n += 256) {
      unsigned u = key[n];
      if ((u & mask) == prefix) atomicAdd(&hist[(u >> shift) & 255], 1);
    }
    __syncthreads();
    if (tid == 0) {
      int cum = 0; int v = 255;
      for (; v > 0; --v) { cum += hist[v]; if (cum >= k) break; }
      if (cum < k) cum += hist[0];  // v==0 fallthrough (always lands here correctly)
      bcast[0] = k - (cum - hist[v]);
      bcast[1] = v;
    }
    __syncthreads();
    k = bcast[0];
    prefix |= ((unsigned)bcast[1]) << shift;
    mask |= (255u << shift);
    __syncthreads();
  }
  const unsigned theta = prefix;
  const int need = k;              // ties (==theta) to take, lowest index first
  const int base = tid * 32;       // contiguous chunks -> deterministic index order
  int c = 0;
  for (int j = 0; j < 32; ++j) if (key[base + j] == theta) ++c;
  tiecnt[tid] = c;
  __syncthreads();
  if (tid == 0) {
    int run = 0;
    for (int i = 0; i < 256; ++i) { int t2 = tiecnt[i]; tiecnt[i] = run; run += t2; }
  }
  __syncthreads();
  int run = tiecnt[tid];
  int* eo = expert_of + b * NN;
  for (int j = 0; j < 32; ++j) {
    int n = base + j;
    unsigned u = key[n];
    bool sel = false;
    if (u > theta) sel = true;
    else if (u == theta) { if (run < need) sel = true; ++run; }
    if (sel) atomicMax(&eo[n], e);   // np scatter: largest expert index wins
  }
}

// ---------------- compact per-(b,e) token lists + gate values ----------------
__global__ __launch_bounds__(256) void k_build(const int* __restrict__ expert_of,
                                               const float* __restrict__ t0,
                                               const float* __restrict__ R,
                                               const float* __restrict__ C,
                                               int* __restrict__ counts,
                                               int* __restrict__ lists,
                                               float* __restrict__ gvals) {
  const long i = (long)blockIdx.x * 256 + threadIdx.x;   // grid=128
  const int e = expert_of[i];
  if (e < 0) return;
  const int b = (int)(i >> 13);
  const int n = (int)(i & (NN - 1));
  const int be = b * EE + e;
  const int pos = atomicAdd(&counts[be], 1);
  const int slot = be * TOPM + pos;
  lists[slot] = n;
  gvals[slot] = expf(t0[i * EE + e] - C[be] - R[i]);
}

// ---------------- gathered GEMM: out[n,:] = g * x[n,:] @ experts[e] ----------------
__global__ __launch_bounds__(256) void k_gemm(const float* __restrict__ x,
                                              const float* __restrict__ W,
                                              const int* __restrict__ counts,
                                              const int* __restrict__ lists,
                                              const float* __restrict__ gvals,
                                              float* __restrict__ out) {
  const int be = blockIdx.z;
  const int b = be >> 3, e = be & 7;
  const int cnt = counts[be];
  const int r0 = blockIdx.y * 64;
  if (r0 >= cnt) return;
  const int c0 = blockIdx.x * 64;
  __shared__ float As[16][68];
  __shared__ float Bs[16][68];
  __shared__ int   rowTok[64];
  __shared__ float rowG[64];
  const int tid = threadIdx.x;
  if (tid < 64) {
    int r = r0 + tid;
    rowTok[tid] = (r < cnt) ? lists[be * TOPM + r] : -1;
    rowG[tid]   = (r < cnt) ? gvals[be * TOPM + r] : 0.f;
  }
  __syncthreads();
  const float* Wb = W + (long)e * DD * OUTD;
  const int ty = tid >> 4, tx = tid & 15;
  float acc[4][4] = {};
  const int ar = tid >> 2;            // 0..63 row
  const int ak = (tid & 3) * 4;       // 0,4,8,12
  const int bk = tid >> 4;            // 0..15
  const int bc = (tid & 15) * 4;      // 0..60
  const int atok = rowTok[ar];
  for (int k0 = 0; k0 < DD; k0 += 16) {
    float4 av = make_float4(0.f, 0.f, 0.f, 0.f);
    if (atok >= 0) av = *(const float4*)(x + ((long)b * NN + atok) * DD + k0 + ak);
    As[ak + 0][ar] = av.x; As[ak + 1][ar] = av.y;
    As[ak + 2][ar] = av.z; As[ak + 3][ar] = av.w;
    float4 wv = *(const float4*)(Wb + (long)(k0 + bk) * OUTD + c0 + bc);
    *(float4*)&Bs[bk][bc] = wv;
    __syncthreads();
#pragma unroll
    for (int k = 0; k < 16; ++k) {
      float4 a = *(const float4*)&As[k][ty * 4];
      float4 bv = *(const float4*)&Bs[k][tx * 4];
      acc[0][0] += a.x * bv.x; acc[0][1] += a.x * bv.y; acc[0][2] += a.x * bv.z; acc[0][3] += a.x * bv.w;
      acc[1][0] += a.y * bv.x; acc[1][1] += a.y * bv.y; acc[1][2] += a.y * bv.z; acc[1][3] += a.y * bv.w;
      acc[2][0] += a.z * bv.x; acc[2][1] += a.z * bv.y; acc[2][2] += a.z * bv.z; acc[2][3] += a.z * bv.w;
      acc[3][0] += a.w * bv.x; acc[3][1] += a.w * bv.y; acc[3][2] += a.w * bv.z; acc[3][3] += a.w * bv.w;
    }
    __syncthreads();
  }
#pragma unroll
  for (int i = 0; i < 4; ++i) {
    int r = ty * 4 + i;
    int tok = rowTok[r];
    if (tok < 0) continue;
    float g = rowG[r];
    float4 o = make_float4(acc[i][0] * g, acc[i][1] * g, acc[i][2] * g, acc[i][3] * g);
    *(float4*)(out + ((long)b * NN + tok) * OUTD + c0 + tx * 4) = o;
  }
}

extern "C" void kernel_launch(void* const* d_in, const int* in_sizes, int n_in,
                              void* d_out, int out_size, void* d_ws, size_t ws_size,
                              hipStream_t stream) {
  const float* x  = (const float*)d_in[0];
  const float* gw = (const float*)d_in[1];
  const float* ex = (const float*)d_in[2];
  float* out = (float*)d_out;

  char* w = (char*)d_ws;
  float* t0        = (float*)(w);                               // 1 MiB
  float* R         = (float*)(w + (1 << 20));                   // 128 KiB
  float* C         = (float*)(w + (1 << 20) + (128 << 10));     // 256 B
  int*   expert_of = (int*)  (w + (1 << 20) + (128 << 10) + 256);         // 128 KiB
  int*   counts    = (int*)  (w + (1 << 20) + (256 << 10) + 512);         // 256 B
  int*   lists     = (int*)  (w + (1 << 20) + (256 << 10) + 1024);        // 128 KiB
  float* gvals     = (float*)(w + (1 << 20) + (384 << 10) + 1024);        // 128 KiB

  hipMemsetAsync(out, 0, (size_t)BB * NN * OUTD * 4, stream);
  hipMemsetAsync(R, 0, (size_t)BB * NN * 4, stream);
  hipMemsetAsync(expert_of, 0xFF, (size_t)BB * NN * 4, stream);
  hipMemsetAsync(counts, 0, (size_t)BB * EE * 4, stream);

  k_gate<<<(BB * NN) / 4, 256, 0, stream>>>(x, gw, t0);
  for (int it = 0; it < ITERS; ++it) {
    k_col<<<BB * EE, 256, 0, stream>>>(t0, R, C);
    k_row<<<(BB * NN) / 256, 256, 0, stream>>>(t0, C, R);
  }
  k_topk<<<BB * EE, 256, 0, stream>>>(t0, R, expert_of);
  k_build<<<(BB * NN) / 256, 256, 0, stream>>>(expert_of, t0, R, C, counts, lists, gvals);

  dim3 g(OUTD / 64, TOPM / 64, BB * EE);
  k_gemm<<<g, 256, 0, stream>>>(x, ex, counts, lists, gvals, out);
}

// Round 2
// 371.646 us; speedup vs baseline: 1.3993x; 1.3993x over previous
//
#include <hip/hip_runtime.h>
#include <hip/hip_bf16.h>

#define BB 4
#define NN 8192
#define DD 512
#define EE 8
#define OUTD 512
#define TOPM 1024
#define EPSV 1e-6f
#define ITERS 8

using s16x8 = __attribute__((ext_vector_type(8))) short;
using f32x4 = __attribute__((ext_vector_type(4))) float;

__device__ __forceinline__ unsigned short f2bf(float f) {
  unsigned u = __float_as_uint(f);
  return (unsigned short)((u + 0x7FFFu + ((u >> 16) & 1u)) >> 16);
}

__device__ __forceinline__ void gll16(const void* g, void* l) {
  __builtin_amdgcn_global_load_lds((const __attribute__((address_space(1))) void*)g,
                                   (__attribute__((address_space(3))) void*)l, 16, 0, 0);
}

// ---------------- gate logits -> t0 = log(max(x@gw, eps)); also x -> bf16 ----------------
__global__ __launch_bounds__(256) void k_gate(const float* __restrict__ x,
                                              const float* __restrict__ gw,
                                              float* __restrict__ t0,
                                              unsigned short* __restrict__ xbf) {
  const int lane = threadIdx.x & 63;
  const int wid  = threadIdx.x >> 6;
  const long row = (long)blockIdx.x * 4 + wid;   // B*N rows, grid=8192
  const float* xr = x + row * DD + lane * 8;
  float4 xa = *(const float4*)(xr);
  float4 xb = *(const float4*)(xr + 4);
  float xv[8] = {xa.x, xa.y, xa.z, xa.w, xb.x, xb.y, xb.z, xb.w};

  s16x8 xo;
#pragma unroll
  for (int j = 0; j < 8; ++j) xo[j] = (short)f2bf(xv[j]);
  *(s16x8*)(xbf + row * DD + lane * 8) = xo;

  float acc[8] = {0.f,0.f,0.f,0.f,0.f,0.f,0.f,0.f};
  const float* gbase = gw + (lane * 8) * EE;
#pragma unroll
  for (int j = 0; j < 8; ++j) {
    float4 g0 = *(const float4*)(gbase + j * EE);
    float4 g1 = *(const float4*)(gbase + j * EE + 4);
    acc[0] += xv[j] * g0.x; acc[1] += xv[j] * g0.y;
    acc[2] += xv[j] * g0.z; acc[3] += xv[j] * g0.w;
    acc[4] += xv[j] * g1.x; acc[5] += xv[j] * g1.y;
    acc[6] += xv[j] * g1.z; acc[7] += xv[j] * g1.w;
  }
#pragma unroll
  for (int off = 32; off; off >>= 1) {
#pragma unroll
    for (int e = 0; e < 8; ++e) acc[e] += __shfl_xor(acc[e], off);
  }
  if (lane < 8) t0[row * EE + lane] = logf(fmaxf(acc[lane], EPSV));
}

// ---------------- experts f32 [e][k][n] -> bf16 transposed [e][n][k] ----------------
__global__ __launch_bounds__(256) void k_wt(const float* __restrict__ W,
                                            unsigned short* __restrict__ WT) {
  __shared__ float tl[32][33];
  const int e = blockIdx.z, k0 = blockIdx.y * 32, n0 = blockIdx.x * 32;
  const int ty = threadIdx.x >> 5, tx = threadIdx.x & 31;
  const float* src = W + ((long)e * DD + k0) * OUTD + n0;
#pragma unroll
  for (int j = 0; j < 4; ++j)
    tl[ty + j * 8][tx] = src[(long)(ty + j * 8) * OUTD + tx];
  __syncthreads();
  unsigned short* dst = WT + ((long)e * OUTD + n0) * DD + k0;
#pragma unroll
  for (int j = 0; j < 4; ++j)
    dst[(long)(ty + j * 8) * DD + tx] = f2bf(tl[tx][ty + j * 8]);
}

// ---------------- fused 8-iteration Sinkhorn, one block per batch ----------------
// thread t owns rows {t, t+1024, ..., t+7168}; t0 rows live in registers.
__global__ __launch_bounds__(1024) void k_sink(const float* __restrict__ t0,
                                               float* __restrict__ R,
                                               float* __restrict__ C) {
  const int b = blockIdx.x, t = threadIdx.x;
  const int wv = t >> 6, ln = t & 63;
  const float* tb = t0 + (long)b * NN * EE;
  float tv[8][8];
#pragma unroll
  for (int j = 0; j < 8; ++j) {
    const float* p = tb + (long)(t + j * 1024) * EE;
    float4 v0 = *(const float4*)p;
    float4 v1 = *(const float4*)(p + 4);
    tv[j][0] = v0.x; tv[j][1] = v0.y; tv[j][2] = v0.z; tv[j][3] = v0.w;
    tv[j][4] = v1.x; tv[j][5] = v1.y; tv[j][6] = v1.z; tv[j][7] = v1.w;
  }
  float Rr[8] = {0.f,0.f,0.f,0.f,0.f,0.f,0.f,0.f};
  __shared__ float redm[16][8], reds[16][8], Csh[8];
  for (int it = 0; it < ITERS; ++it) {
    // col step: C[e] = LSE_n(t0 - R)
#pragma unroll
    for (int e = 0; e < 8; ++e) {
      float M = tv[0][e] - Rr[0];
#pragma unroll
      for (int j = 1; j < 8; ++j) M = fmaxf(M, tv[j][e] - Rr[j]);
#pragma unroll
      for (int o = 32; o; o >>= 1) M = fmaxf(M, __shfl_xor(M, o));
      float sv = 0.f;
#pragma unroll
      for (int j = 0; j < 8; ++j) sv += expf(tv[j][e] - Rr[j] - M);
#pragma unroll
      for (int o = 32; o; o >>= 1) sv += __shfl_xor(sv, o);
      if (ln == 0) { redm[wv][e] = M; reds[wv][e] = sv; }
    }
    __syncthreads();
    if (t < 8) {
      float M = redm[0][t], S = reds[0][t];
      for (int q = 1; q < 16; ++q) {
        float mo = redm[q][t], so = reds[q][t];
        float Mx = fmaxf(M, mo);
        S = S * expf(M - Mx) + so * expf(mo - Mx);
        M = Mx;
      }
      Csh[t] = M + logf(S);
    }
    __syncthreads();
    float c8[8];
#pragma unroll
    for (int e = 0; e < 8; ++e) c8[e] = Csh[e];
    // row step: R[n] = LSE_e(t0 - C)
#pragma unroll
    for (int j = 0; j < 8; ++j) {
      float mx = tv[j][0] - c8[0];
#pragma unroll
      for (int e = 1; e < 8; ++e) mx = fmaxf(mx, tv[j][e] - c8[e]);
      float ss = 0.f;
#pragma unroll
      for (int e = 0; e < 8; ++e) ss += expf(tv[j][e] - c8[e] - mx);
      Rr[j] = mx + logf(ss);
    }
  }
#pragma unroll
  for (int j = 0; j < 8; ++j) R[b * NN + t + j * 1024] = Rr[j];
  if (t < 8) C[b * EE + t] = Csh[t];
}

// ---------------- exact top-1024 per (b,e) column via radix select ----------------
__global__ __launch_bounds__(256) void k_topk(const float* __restrict__ t0,
                                              const float* __restrict__ R,
                                              int* __restrict__ expert_of) {
  __shared__ unsigned key[NN];
  __shared__ int hist[256];
  __shared__ int bcast[2];
  __shared__ int tiecnt[256];
  const int b = blockIdx.x >> 3, e = blockIdx.x & 7;
  const int tid = threadIdx.x;
  const float* t = t0 + (long)b * NN * EE + e;
  const float* Rb = R + b * NN;
  for (int n = tid; n < NN; n += 256) {
    float f = t[n * EE] - Rb[n];
    unsigned u = __float_as_uint(f);
    u = (u & 0x80000000u) ? ~u : (u | 0x80000000u);
    key[n] = u;
  }
  __syncthreads();
  unsigned prefix = 0, mask = 0;
  int k = TOPM;
  for (int shift = 24; shift >= 0; shift -= 8) {
    hist[tid] = 0;
    __syncthreads();
    for (int n = tid; n < NN; n += 256) {
      unsigned u = key[n];
      if ((u & mask) == prefix) atomicAdd(&hist[(u >> shift) & 255], 1);
    }
    __syncthreads();
    if (tid == 0) {
      int cum = 0; int v = 255;
      for (; v > 0; --v) { cum += hist[v]; if (cum >= k) break; }
      if (cum < k) cum += hist[0];
      bcast[0] = k - (cum - hist[v]);
      bcast[1] = v;
    }
    __syncthreads();
    k = bcast[0];
    prefix |= ((unsigned)bcast[1]) << shift;
    mask |= (255u << shift);
    __syncthreads();
  }
  const unsigned theta = prefix;
  const int need = k;
  const int base = tid * 32;
  int c = 0;
  for (int j = 0; j < 32; ++j) if (key[base + j] == theta) ++c;
  tiecnt[tid] = c;
  __syncthreads();
  if (tid == 0) {
    int run = 0;
    for (int i = 0; i < 256; ++i) { int t2 = tiecnt[i]; tiecnt[i] = run; run += t2; }
  }
  __syncthreads();
  int run = tiecnt[tid];
  int* eo = expert_of + b * NN;
  for (int j = 0; j < 32; ++j) {
    int n = base + j;
    unsigned u = key[n];
    bool sel = false;
    if (u > theta) sel = true;
    else if (u == theta) { if (run < need) sel = true; ++run; }
    if (sel) atomicMax(&eo[n], e);
  }
}

// ---------------- compact per-(b,e) token lists + gate values ----------------
__global__ __launch_bounds__(256) void k_build(const int* __restrict__ expert_of,
                                               const float* __restrict__ t0,
                                               const float* __restrict__ R,
                                               const float* __restrict__ C,
                                               int* __restrict__ counts,
                                               int* __restrict__ lists,
                                               float* __restrict__ gvals) {
  const long i = (long)blockIdx.x * 256 + threadIdx.x;
  const int e = expert_of[i];
  if (e < 0) return;
  const int b = (int)(i >> 13);
  const int n = (int)(i & (NN - 1));
  const int be = b * EE + e;
  const int pos = atomicAdd(&counts[be], 1);
  const int slot = be * TOPM + pos;
  lists[slot] = n;
  gvals[slot] = expf(t0[i * EE + e] - C[be] - R[i]);
}

// ---------------- zero output rows of unselected tokens ----------------
__global__ __launch_bounds__(256) void k_zero(const int* __restrict__ eo,
                                              float* __restrict__ out) {
  const int row = blockIdx.x * 4 + (threadIdx.x >> 6);
  if (eo[row] >= 0) return;
  const int ln = threadIdx.x & 63;
  float4 z = make_float4(0.f, 0.f, 0.f, 0.f);
  float4* p = (float4*)(out + (long)row * OUTD) + ln;
  p[0] = z; p[64] = z;
}

// ---------------- gathered bf16 MFMA GEMM: out[tok,:] = g * x[tok,:] @ W[e] ----------------
__global__ __launch_bounds__(256) void k_gemm(const unsigned short* __restrict__ xbf,
                                              const unsigned short* __restrict__ WT,
                                              const int* __restrict__ counts,
                                              const int* __restrict__ lists,
                                              const float* __restrict__ gvals,
                                              float* __restrict__ out) {
  const int be = blockIdx.z;
  const int b = be >> 3, e = be & 7;
  const int cnt = counts[be];
  const int r0 = blockIdx.y * 128;
  if (r0 >= cnt) return;
  const int c0 = blockIdx.x * 128;

  __shared__ unsigned short As[128 * 32];   // [row][k] bf16, k-slot XOR-swizzled
  __shared__ unsigned short Bs[128 * 32];   // [col][k] bf16 (from WT), same swizzle
  __shared__ int   rowTok[128];
  __shared__ float rowG[128];

  const int tid = threadIdx.x;
  if (tid < 128) {
    int r = r0 + tid;
    rowTok[tid] = (r < cnt) ? lists[be * TOPM + r] : -1;
    rowG[tid]   = (r < cnt) ? gvals[be * TOPM + r] : 0.f;
  }
  __syncthreads();

  const int w = tid >> 6, l = tid & 63;
  // staging: 8 chunks of 16 rows x 32 k (1 KiB); wave w stages chunks 2w, 2w+1 for A and B.
  const int c_a = 2 * w, c_b = 2 * w + 1;
  const int rr = l >> 2;
  const int slot = l & 3;
  const int ra0 = c_a * 16 + rr;
  const int ra1 = c_b * 16 + rr;
  const int kg0 = slot ^ ((ra0 >> 1) & 3);   // pre-swizzled global k-chunk (involution)
  const int kg1 = slot ^ ((ra1 >> 1) & 3);
  int tA0 = rowTok[ra0]; if (tA0 < 0) tA0 = 0;
  int tA1 = rowTok[ra1]; if (tA1 < 0) tA1 = 0;
  const unsigned short* gA0 = xbf + ((long)b * NN + tA0) * DD + kg0 * 8;
  const unsigned short* gA1 = xbf + ((long)b * NN + tA1) * DD + kg1 * 8;
  const unsigned short* gB0 = WT + ((long)e * OUTD + c0 + ra0) * DD + kg0 * 8;
  const unsigned short* gB1 = WT + ((long)e * OUTD + c0 + ra1) * DD + kg1 * 8;
  unsigned short* lA0 = As + c_a * 512;
  unsigned short* lA1 = As + c_b * 512;
  unsigned short* lB0 = Bs + c_a * 512;
  unsigned short* lB1 = Bs + c_b * 512;

  const int wr = w >> 1, wc = w & 1;
  const int fr = l & 15, fq = l >> 4;
  int aoff[4], boff[4];
#pragma unroll
  for (int m = 0; m < 4; ++m) {
    int row = wr * 64 + m * 16 + fr;
    aoff[m] = row * 32 + (fq ^ ((row >> 1) & 3)) * 8;   // swizzled read matches staged layout
    int col = wc * 64 + m * 16 + fr;
    boff[m] = col * 32 + (fq ^ ((col >> 1) & 3)) * 8;
  }

  f32x4 acc[4][4] = {};

  gll16(gA0, lA0); gll16(gA1, lA1);
  gll16(gB0, lB0); gll16(gB1, lB1);

  for (int ks = 0; ks < 16; ++ks) {
    __syncthreads();                       // staging visible (vmcnt drained at barrier)
    s16x8 af[4], bfr[4];
#pragma unroll
    for (int m = 0; m < 4; ++m) af[m] = *(const s16x8*)(As + aoff[m]);
#pragma unroll
    for (int n = 0; n < 4; ++n) bfr[n] = *(const s16x8*)(Bs + boff[n]);
    __syncthreads();                       // frags in regs; safe to restage
    if (ks < 15) {
      int off = (ks + 1) * 32;
      gll16(gA0 + off, lA0); gll16(gA1 + off, lA1);
      gll16(gB0 + off, lB0); gll16(gB1 + off, lB1);
    }
#pragma unroll
    for (int m = 0; m < 4; ++m)
#pragma unroll
      for (int n = 0; n < 4; ++n)
        acc[m][n] = __builtin_amdgcn_mfma_f32_16x16x32_bf16(af[m], bfr[n], acc[m][n], 0, 0, 0);
  }

  // epilogue: C/D layout col=lane&15, row=(lane>>4)*4+reg
#pragma unroll
  for (int m = 0; m < 4; ++m) {
    int rbase = wr * 64 + m * 16 + fq * 4;
    int tok[4]; float g[4];
#pragma unroll
    for (int j = 0; j < 4; ++j) { tok[j] = rowTok[rbase + j]; g[j] = rowG[rbase + j]; }
#pragma unroll
    for (int n = 0; n < 4; ++n) {
      int col = c0 + wc * 64 + n * 16 + fr;
#pragma unroll
      for (int j = 0; j < 4; ++j) {
        if (tok[j] >= 0)
          out[((long)b * NN + tok[j]) * OUTD + col] = acc[m][n][j] * g[j];
      }
    }
  }
}

extern "C" void kernel_launch(void* const* d_in, const int* in_sizes, int n_in,
                              void* d_out, int out_size, void* d_ws, size_t ws_size,
                              hipStream_t stream) {
  const float* x  = (const float*)d_in[0];
  const float* gw = (const float*)d_in[1];
  const float* ex = (const float*)d_in[2];
  float* out = (float*)d_out;

  char* wsb = (char*)d_ws;
  float*          t0     = (float*)(wsb);                          // 1 MiB
  unsigned short* xbf    = (unsigned short*)(wsb + (1l << 20));    // 32 MiB
  unsigned short* WT     = (unsigned short*)(wsb + (33l << 20));   // 4 MiB
  float*          R      = (float*)(wsb + (37l << 20));                    // 128 KiB
  int*            eo     = (int*)  (wsb + (37l << 20) + (128l << 10));     // 128 KiB
  int*            lists  = (int*)  (wsb + (37l << 20) + (256l << 10));     // 128 KiB
  float*          gvals  = (float*)(wsb + (37l << 20) + (384l << 10));     // 128 KiB
  float*          C      = (float*)(wsb + (37l << 20) + (512l << 10));     // 32 B
  int*            counts = (int*)  (wsb + (37l << 20) + (512l << 10) + 1024); // 128 B

  hipMemsetAsync(eo, 0xFF, (size_t)BB * NN * 4, stream);
  hipMemsetAsync(counts, 0, (size_t)BB * EE * 4, stream);

  k_gate<<<(BB * NN) / 4, 256, 0, stream>>>(x, gw, t0, xbf);
  k_wt<<<dim3(OUTD / 32, DD / 32, EE), 256, 0, stream>>>(ex, WT);
  k_sink<<<BB, 1024, 0, stream>>>(t0, R, C);
  k_topk<<<BB * EE, 256, 0, stream>>>(t0, R, eo);
  k_build<<<(BB * NN) / 256, 256, 0, stream>>>(eo, t0, R, C, counts, lists, gvals);
  k_zero<<<(BB * NN) / 4, 256, 0, stream>>>(eo, out);
  k_gemm<<<dim3(OUTD / 128, TOPM / 128, BB * EE), 256, 0, stream>>>(xbf, WT, counts, lists, gvals, out);
}